// Round 8
// baseline (10341.599 us; speedup 1.0000x reference)
//
#include <hip/hip_runtime.h>
#include <math.h>

// ---------------------------------------------------------------------------
// SimpleRNN (2-layer LSTM, H=1024, T=4096 sequential steps, batch=1 effective)
//
//   k_clear    : zero the packet buffers (tags must start invalid)
//   k_prep     : gather x (step-major), combine biases
//   gemm_nt    : C[M,N] = A[M,K] @ B[N,K]^T + bias
//   lstm_fused : persistent 256-block kernel, 128 L0 + 128 L1 blocks (R7/R10
//                split skeleton). SYNC = DATA: h moves as 8-byte packets
//                {float h, int tag}, relaxed agent-scope.
//
//   Evidence trail on the ~2.2us round:
//     R7  poll traffic -14%        -> round -6%   (secondary)
//     R10 on-chain compute halved  -> round -3%   (secondary)
//     R11 VALU-busy spin           -> round -1%   (clock droop ruled out)
//     R12 atomic-swap store +poll4 -> round +32%  (REGRESSION, reverted)
//     R13 = R11 revert, reproduced 9.04 ms (round 2.21us)
//   R14 (this): PRODUCER STORE RETIREMENT off the chain. vmcnt is an
//   in-order counter tracking loads AND stores, so:
//     (a) __syncthreads = s_waitcnt vmcnt(0) + s_barrier: round t's packet
//         store stalls the WHOLE block at round t+1's B1 until MALL-acked.
//     (b) storer threads (tid<8) also poll: their tag check's vmcnt(0)
//         waits (in-order) for their own store ack; block detect = max
//         over threads -> storers gate it.
//   Fix: (1) chain barriers -> s_waitcnt lgkmcnt(0) + s_barrier only (all
//   cross-thread data at these barriers is LDS); (2) tid 0-7 never poll;
//   tid 8-15 cover words 0-7 via a uniform predicated double-poll.
//   All other structure/memory patterns byte-identical to R13.
// ---------------------------------------------------------------------------

#define T_STEPS 4096
#define HID 1024
#define UPB 8            // hidden units per block
#define NBLK 256         // persistent blocks (128 per layer)

typedef unsigned long long u64;

#define AGENT_LD64(p) __hip_atomic_load((p), __ATOMIC_RELAXED, __HIP_MEMORY_SCOPE_AGENT)
#define AGENT_ST64(p, v) __hip_atomic_store((p), (v), __ATOMIC_RELAXED, __HIP_MEMORY_SCOPE_AGENT)

__device__ __forceinline__ u64 pack_h(float h, int tag) {
  return (u64)__float_as_uint(h) | ((u64)(unsigned)tag << 32);
}
__device__ __forceinline__ float pkt_val(u64 v) { return __uint_as_float((unsigned)v); }
__device__ __forceinline__ int pkt_tag(u64 v) { return (int)(v >> 32); }

__device__ __forceinline__ float fast_sigm(float x) {
  return __builtin_amdgcn_rcpf(1.f + __expf(-x));
}
__device__ __forceinline__ float fast_tanh(float x) {
  return 2.f * __builtin_amdgcn_rcpf(1.f + __expf(-2.f * x)) - 1.f;
}

// Barrier WITHOUT the vmcnt(0) drain __syncthreads would emit: LDS-only
// ordering (lgkmcnt) + s_barrier. Outstanding global packet stores keep
// flying across it. Memory clobbers pin C++-level ordering (guide rule #18;
// pattern proven in the 8-phase GEMM template, learn_hip m201).
__device__ __forceinline__ void bar_lds() {
  asm volatile("s_waitcnt lgkmcnt(0)" ::: "memory");
  __builtin_amdgcn_s_barrier();
  asm volatile("" ::: "memory");
}

// Busy-spin unit: 8 dependent v_fmac_f32 (volatile -> always issued).
__device__ __forceinline__ void spin_fma(float* j) {
  const float eps = 1.0e-12f;
#pragma unroll
  for (int z = 0; z < 8; z++)
    asm volatile("v_fmac_f32 %0, %1, %1" : "+v"(*j) : "v"(eps));
}

// Pace: spin (no memory traffic, VALU busy) until ~half the expected period
// has elapsed since the previous detect. per==0 disables (warmup rounds).
__device__ __forceinline__ void pace_wait(u64 t_last, u64 per, float* j) {
  if (per) {
    u64 target = t_last + (per >> 1);
    while ((long long)(__builtin_amdgcn_s_memrealtime() - target) < 0)
      spin_fma(j);
  }
}
// EWMA period update (clamped against scheduler hiccups).
__device__ __forceinline__ void pace_update(u64* t_last, u64* per) {
  u64 now = __builtin_amdgcn_s_memrealtime();
  if (*t_last) {
    u64 d = now - *t_last;
    if (d > 1024) d = 1024;                 // ~10 us cap @100 MHz wall clock
    *per = *per ? ((*per * 3 + d) >> 2) : d;
  }
  *t_last = now;
}

__global__ void k_clear(u64* __restrict__ p, long n) {
  long i = (long)blockIdx.x * blockDim.x + threadIdx.x;
  long stride = (long)gridDim.x * blockDim.x;
  for (; i < n; i += stride) p[i] = 0ULL;
}

__global__ void k_prep(const float* __restrict__ inputs,
                       const float* __restrict__ b_ih0, const float* __restrict__ b_hh0,
                       const float* __restrict__ b_ih1, const float* __restrict__ b_hh1,
                       float* __restrict__ xg, float* __restrict__ bsum0,
                       float* __restrict__ b1sum) {
  int i = blockIdx.x * 256 + threadIdx.x;   // grid covers 262144
  if (i < T_STEPS * 64) {
    int t = i >> 6, d = i & 63;
    // x[t] = inputs[sample = t%32, step = t/32, :]
    xg[i] = inputs[(t & 31) * 8192 + (t >> 5) * 64 + d];
  }
  if (i < 4096) {
    bsum0[i] = b_ih0[i] + b_hh0[i];
    b1sum[i] = b_ih1[i] + b_hh1[i];
  }
}

// C = A @ B^T + bias.  A: M x K, B: N x K (both row-major, K contiguous).
// 128x128 tile, BK=8, 256 threads, 8x8 micro-tile per thread.
__global__ __launch_bounds__(256) void gemm_nt(
    const float* __restrict__ A, const float* __restrict__ B,
    const float* __restrict__ bias, float* __restrict__ C,
    int M, int N, int K, int mode) {
  __shared__ float As[8][128];
  __shared__ float Bs[8][128];
  const int tid = threadIdx.x;
  const int bm = blockIdx.x * 128;
  const int bn = blockIdx.y * 128;
  const int tm = tid >> 4;
  const int tn = tid & 15;
  const int lr = tid >> 1;
  const int lk = (tid & 1) * 4;

  float acc[8][8];
#pragma unroll
  for (int i = 0; i < 8; i++)
#pragma unroll
    for (int j = 0; j < 8; j++) acc[i][j] = 0.f;

  const float* Ap = A + (long)(bm + lr) * K + lk;
  const bool bvalid = (bn + lr) < N;
  const float* Bp = B + (long)(bvalid ? (bn + lr) : 0) * K + lk;

  for (int k0 = 0; k0 < K; k0 += 8) {
    float4 av = *(const float4*)(Ap + k0);
    float4 bv = bvalid ? *(const float4*)(Bp + k0) : make_float4(0.f, 0.f, 0.f, 0.f);
    As[lk + 0][lr] = av.x; As[lk + 1][lr] = av.y;
    As[lk + 2][lr] = av.z; As[lk + 3][lr] = av.w;
    Bs[lk + 0][lr] = bv.x; Bs[lk + 1][lr] = bv.y;
    Bs[lk + 2][lr] = bv.z; Bs[lk + 3][lr] = bv.w;
    __syncthreads();
#pragma unroll
    for (int kk = 0; kk < 8; kk++) {
      float a[8], b[8];
      *(float4*)&a[0] = *(const float4*)&As[kk][tm * 8];
      *(float4*)&a[4] = *(const float4*)&As[kk][tm * 8 + 4];
      *(float4*)&b[0] = *(const float4*)&Bs[kk][tn * 8];
      *(float4*)&b[4] = *(const float4*)&Bs[kk][tn * 8 + 4];
#pragma unroll
      for (int i = 0; i < 8; i++)
#pragma unroll
        for (int j = 0; j < 8; j++) acc[i][j] = fmaf(a[i], b[j], acc[i][j]);
    }
    __syncthreads();
  }

  const int n0 = bn + tn * 8;
  if (n0 < N) {
    float bb[8];
#pragma unroll
    for (int j = 0; j < 8; j++) bb[j] = bias[n0 + j];
#pragma unroll
    for (int i = 0; i < 8; i++) {
      int m = bm + tm * 8 + i;
      float4 v0, v1;
      v0.x = acc[i][0] + bb[0]; v0.y = acc[i][1] + bb[1];
      v0.z = acc[i][2] + bb[2]; v0.w = acc[i][3] + bb[3];
      v1.x = acc[i][4] + bb[4]; v1.y = acc[i][5] + bb[5];
      v1.z = acc[i][6] + bb[6]; v1.w = acc[i][7] + bb[7];
      if (mode == 0) {
        long o = (long)m * N + n0;
        *(float4*)&C[o] = v0; *(float4*)&C[o + 4] = v1;
      } else {
        long o = (long)(m & 31) * 8192 + (long)(m >> 5) * 64 + n0;
        *(float4*)&C[o] = v0; *(float4*)&C[o + 4] = v1;
      }
    }
  }
}

// Fused 2-layer recurrence. 256 blocks x 1024 threads (16 waves), 1 block/CU.
// Wave w owns local rows 2w, 2w+1 (row rr: gate rr>>3, unit rr&7);
// lane covers k = lane + 64*m (stride-64 LDS reads: conflict-free).
__global__ __launch_bounds__(1024, 1) void lstm_fused(
    const float* __restrict__ pre0,   // T x 4096 (layer-0 biases included)
    const float* __restrict__ Whh0,   // 4096 x 1024
    const float* __restrict__ Wih1,   // 4096 x 1024
    const float* __restrict__ Whh1,   // 4096 x 1024
    const float* __restrict__ b1sum,  // 4096
    u64* __restrict__ pk0,            // T x 1024 packets {h0, tag=t+1}
    u64* __restrict__ pk1,            // T x 1024 packets {h1, tag=t+1}
    float* __restrict__ h1_hist) {    // T x 1024 plain (for output GEMM)
  __shared__ float ha_lds[HID];       // 4 KB
  __shared__ float hb_lds[HID];       // 4 KB (layer-1 only)
  __shared__ float scr[32];
  const int b = blockIdx.x;
  const int tid = threadIdx.x;
  const int wave = tid >> 6;          // wave w owns local rows 2w, 2w+1
  const int lane = tid & 63;
  float junk = 0.f;                   // spin accumulator (kept live below)

  if (b < 128) {
    // ----------------------------- layer 0 -------------------------------
    const int j0 = b * UPB;
    // weight rows in VGPRs: w0[m] = Whh0[row(2w)][lane+64m], w1 likewise
    float w0[16], w1[16];
    {
      int r0 = 2 * wave, r1 = 2 * wave + 1;
      const float* s0 = Whh0 + (long)((r0 >> 3) * HID + j0 + (r0 & 7)) * HID + lane;
      const float* s1 = Whh0 + (long)((r1 >> 3) * HID + j0 + (r1 & 7)) * HID + lane;
#pragma unroll
      for (int m = 0; m < 16; m++) { w0[m] = s0[m << 6]; w1[m] = s1[m << 6]; }
    }
    float c_state = 0.f;              // valid in tid 0..7
    u64 t_last = 0, per = 0;          // pacing state (100 MHz wall ticks)
    __syncthreads();

    for (int t = 0; t < T_STEPS; t++) {
      float preval = 0.f;             // in-register; load overlaps the poll
      if (tid < 32)
        preval = pre0[(long)t * 4096 + ((tid >> 3) << 10) + j0 + (tid & 7)];

      if (t > 0) {
        // tid 0-7 (the storers) never poll: their store ack stays off-chain.
        if (tid >= 8) {
          const u64* p = pk0 + (long)(t - 1) * HID + tid;
          const bool dbl = (tid < 16);
          const u64* p2 = pk0 + (long)(t - 1) * HID + (tid & 7);
          pace_wait(t_last, per, &junk);
          u64 v = 0, v2 = 0;
          bool ok1 = false, ok2 = !dbl;
          for (;;) {
            if (!ok1) v = AGENT_LD64(p);
            if (!ok2) v2 = AGENT_LD64(p2);
            ok1 = ok1 || (pkt_tag(v) == t);
            ok2 = ok2 || (pkt_tag(v2) == t);
            if (ok1 && ok2) break;
            spin_fma(&junk);          // VALU-busy wait (clock hold)
          }
          pace_update(&t_last, &per);
          ha_lds[tid] = pkt_val(v);
          if (dbl) ha_lds[tid & 7] = pkt_val(v2);
        }
      } else {
        ha_lds[tid] = 0.f;
      }
      bar_lds();                      // B1 (no vmcnt drain)

      float s0 = 0.f, s1 = 0.f;
#pragma unroll
      for (int m = 0; m < 16; m++) {
        float hv = ha_lds[lane + (m << 6)];
        s0 = fmaf(w0[m], hv, s0);
        s1 = fmaf(w1[m], hv, s1);
      }
#pragma unroll
      for (int off = 32; off >= 1; off >>= 1) {
        s0 += __shfl_xor(s0, off, 64);
        s1 += __shfl_xor(s1, off, 64);
      }
      if (lane == 0) { scr[wave * 2] = s0; scr[wave * 2 + 1] = s1; }
      bar_lds();                      // B2 (no vmcnt drain)

      // Parallel tail: 32 lanes of wave 0 = one (gate,unit) each.
      if (tid < 32) {
        float sum = scr[tid] + preval;
        float a = ((tid >> 3) == 2) ? fast_tanh(sum) : fast_sigm(sum);
        float af = __shfl(a,  8 + (tid & 7), 64);
        float ag = __shfl(a, 16 + (tid & 7), 64);
        float ao = __shfl(a, 24 + (tid & 7), 64);
        if (tid < 8) {                // a here = sigm(i) of unit tid
          c_state = af * c_state + a * ag;
          float h = ao * fast_tanh(c_state);
          // 8 consecutive u64 = one 64B line: coalesces into one write
          AGENT_ST64(&pk0[(long)t * HID + j0 + tid], pack_h(h, t + 1));
        }
      }
    }
    if (junk == 123456.789f) ha_lds[0] = junk;   // unreachable: keeps junk live
  } else {
    // ----------------------------- layer 1 -------------------------------
    const int j0 = (b - 128) * UPB;
    float wi0[16], wi1[16], wh0[16], wh1[16];
    {
      int r0 = 2 * wave, r1 = 2 * wave + 1;
      long o0 = (long)((r0 >> 3) * HID + j0 + (r0 & 7)) * HID + lane;
      long o1 = (long)((r1 >> 3) * HID + j0 + (r1 & 7)) * HID + lane;
      const float* a0 = Wih1 + o0; const float* a1 = Wih1 + o1;
      const float* c0 = Whh1 + o0; const float* c1 = Whh1 + o1;
#pragma unroll
      for (int m = 0; m < 16; m++) {
        wi0[m] = a0[m << 6]; wi1[m] = a1[m << 6];
        wh0[m] = c0[m << 6]; wh1[m] = c1[m << 6];
      }
    }
    float b1v = 0.f;                  // in-register bias (gate,unit) of tid<32
    if (tid < 32) b1v = b1sum[((tid >> 3) << 10) + j0 + (tid & 7)];
    float c_state = 0.f;              // valid in tid 0..7
    u64 t_last = 0, per = 0;
    __syncthreads();

    // ---- setup: sA = Wih1 @ h0[0] per-lane partials (off-chain, once) ----
    float sA0 = 0.f, sA1 = 0.f;
    {
      const u64* p = pk0 + tid;
      u64 v;
      for (;;) {
        v = AGENT_LD64(p);
        if (pkt_tag(v) == 1) break;
        spin_fma(&junk);
      }
      ha_lds[tid] = pkt_val(v);
      __syncthreads();
#pragma unroll
      for (int m = 0; m < 16; m++) {
        float av = ha_lds[lane + (m << 6)];
        sA0 = fmaf(wi0[m], av, sA0);
        sA1 = fmaf(wi1[m], av, sA1);
      }
    }

    for (int r = 1; r <= T_STEPS; r++) {   // computes h1[r-1]
      // ---- chain: detect pk1[r-2] only (single tag; storers exempt) ------
      if (r >= 2) {
        if (tid >= 8) {
          const u64* p = pk1 + (long)(r - 2) * HID + tid;
          const bool dbl = (tid < 16);
          const u64* p2 = pk1 + (long)(r - 2) * HID + (tid & 7);
          pace_wait(t_last, per, &junk);
          u64 v = 0, v2 = 0;
          bool ok1 = false, ok2 = !dbl;
          for (;;) {
            if (!ok1) v = AGENT_LD64(p);
            if (!ok2) v2 = AGENT_LD64(p2);
            ok1 = ok1 || (pkt_tag(v) == r - 1);
            ok2 = ok2 || (pkt_tag(v2) == r - 1);
            if (ok1 && ok2) break;
            spin_fma(&junk);
          }
          pace_update(&t_last, &per);
          hb_lds[tid] = pkt_val(v);
          if (dbl) hb_lds[tid & 7] = pkt_val(v2);
        }
      } else {
        hb_lds[tid] = 0.f;
      }
      bar_lds();                      // B1 (no vmcnt drain)

      // ---- on-chain dot: Whh1 term only (sA carried in registers) --------
      float s0 = sA0, s1 = sA1;
#pragma unroll
      for (int m = 0; m < 16; m++) {
        float bv = hb_lds[lane + (m << 6)];
        s0 = fmaf(wh0[m], bv, s0);
        s1 = fmaf(wh1[m], bv, s1);
      }
#pragma unroll
      for (int off = 32; off >= 1; off >>= 1) {
        s0 += __shfl_xor(s0, off, 64);
        s1 += __shfl_xor(s1, off, 64);
      }
      if (lane == 0) { scr[wave * 2] = s0; scr[wave * 2 + 1] = s1; }
      bar_lds();                      // B2 (no vmcnt drain)

      // ---- parallel tail + chain store -----------------------------------
      if (tid < 32) {
        float sum = scr[tid] + b1v;
        float a = ((tid >> 3) == 2) ? fast_tanh(sum) : fast_sigm(sum);
        float af = __shfl(a,  8 + (tid & 7), 64);
        float ag = __shfl(a, 16 + (tid & 7), 64);
        float ao = __shfl(a, 24 + (tid & 7), 64);
        if (tid < 8) {
          c_state = af * c_state + a * ag;
          float h = ao * fast_tanh(c_state);
          AGENT_ST64(&pk1[(long)(r - 1) * HID + j0 + tid], pack_h(h, r));
          h1_hist[(long)(r - 1) * HID + j0 + tid] = h;   // for out GEMM
        }
      }

      // ---- off-chain (store->detect shadow): sA for next round -----------
      if (r < T_STEPS) {
        if (tid >= 8) {
          const u64* p = pk0 + (long)r * HID + tid;   // h0[r], 1 round stale
          const bool dbl = (tid < 16);
          const u64* p2 = pk0 + (long)r * HID + (tid & 7);
          u64 v = 0, v2 = 0;
          bool ok1 = false, ok2 = !dbl;
          for (;;) {
            if (!ok1) v = AGENT_LD64(p);
            if (!ok2) v2 = AGENT_LD64(p2);
            ok1 = ok1 || (pkt_tag(v) == r + 1);
            ok2 = ok2 || (pkt_tag(v2) == r + 1);
            if (ok1 && ok2) break;
            spin_fma(&junk);
          }
          ha_lds[tid] = pkt_val(v);
          if (dbl) ha_lds[tid & 7] = pkt_val(v2);
        }
        bar_lds();                    // B3 (off-chain, no vmcnt drain)
        float n0 = 0.f, n1 = 0.f;
#pragma unroll
        for (int m = 0; m < 16; m++) {
          float av = ha_lds[lane + (m << 6)];
          n0 = fmaf(wi0[m], av, n0);
          n1 = fmaf(wi1[m], av, n1);
        }
        sA0 = n0; sA1 = n1;
      }
    }
    if (junk == 123456.789f) hb_lds[0] = junk;   // unreachable: keeps junk live
  }
}

extern "C" void kernel_launch(void* const* d_in, const int* in_sizes, int n_in,
                              void* d_out, int out_size, void* d_ws, size_t ws_size,
                              hipStream_t stream) {
  const float* inputs = (const float*)d_in[0];
  const float* W_in  = (const float*)d_in[1];
  const float* b_in  = (const float*)d_in[2];
  const float* W_ih0 = (const float*)d_in[3];
  const float* W_hh0 = (const float*)d_in[4];
  const float* b_ih0 = (const float*)d_in[5];
  const float* b_hh0 = (const float*)d_in[6];
  const float* W_ih1 = (const float*)d_in[7];
  const float* W_hh1 = (const float*)d_in[8];
  const float* b_ih1 = (const float*)d_in[9];
  const float* b_hh1 = (const float*)d_in[10];
  const float* W_out = (const float*)d_in[11];
  const float* b_out = (const float*)d_in[12];
  float* out = (float*)d_out;

  char* ws = (char*)d_ws;
  float* pre_big = (float*)(ws);                          // [0,64) MB: pre0
  u64*   pk0     = (u64*)  (ws + ((size_t)64 << 20));     // [64,96) MB
  u64*   pk1     = (u64*)  (ws + ((size_t)96 << 20));     // [96,128) MB
  float* zbuf    = (float*)(ws + ((size_t)128 << 20));    // [128,144) MB: z, then h1
  float* xg      = (float*)(ws + ((size_t)144 << 20));    // 1 MB
  float* bsum0   = (float*)(ws + ((size_t)145 << 20));    // 16 KB
  float* b1sum   = (float*)(ws + ((size_t)145 << 20) + 16384);

  // 0) invalidate packet tags (64 MB zeros) + gather x + combine biases
  k_clear<<<2048, 256, 0, stream>>>(pk0, (long)2 * T_STEPS * HID);
  k_prep<<<1024, 256, 0, stream>>>(inputs, b_ih0, b_hh0, b_ih1, b_hh1,
                                   xg, bsum0, b1sum);
  // 1) z = x @ W_in^T + b_in            (4096 x 1024, K=64)
  gemm_nt<<<dim3(32, 8), 256, 0, stream>>>(xg, W_in, b_in, zbuf,
                                           T_STEPS, HID, 64, 0);
  // 2) pre0 = z @ W_ih0^T + (b_ih0+b_hh0)   (4096 x 4096, K=1024)
  gemm_nt<<<dim3(32, 32), 256, 0, stream>>>(zbuf, W_ih0, bsum0, pre_big,
                                            T_STEPS, 4096, HID, 0);
  // 3) fused pipelined 2-layer recurrence (h1 -> zbuf)
  lstm_fused<<<NBLK, 1024, 0, stream>>>(pre_big, W_hh0, W_ih1, W_hh1, b1sum,
                                        pk0, pk1, zbuf);
  // 4) y = h1 @ W_out^T + b_out, scattered to (samples, steps, out)
  gemm_nt<<<dim3(32, 1), 256, 0, stream>>>(zbuf, W_out, b_out, out,
                                           T_STEPS, 64, HID, 1);
}

// Round 9
// 9825.745 us; speedup vs baseline: 1.0525x; 1.0525x over previous
//
#include <hip/hip_runtime.h>
#include <math.h>

// ---------------------------------------------------------------------------
// SimpleRNN (2-layer LSTM, H=1024, T=4096 sequential steps, batch=1 effective)
//
//   k_clear    : zero the packet buffers (tags must start invalid)
//   k_prep     : gather x (step-major), combine biases
//   gemm_nt    : C[M,N] = A[M,K] @ B[N,K]^T + bias
//   lstm_fused : persistent 256-block kernel, 128 L0 + 128 L1 blocks (R7/R10
//                split skeleton). SYNC = DATA: h moves as 8-byte packets
//                {float h, int tag}, relaxed agent-scope.
//
//   FINAL (R15 = R13 = R11, best verified 9.02-9.04 ms kernel):
//   Complete single-variable evidence trail on the ~2.2us round:
//     R7  poll traffic -14%          -> round -6%  (secondary)
//     R10 on-chain compute halved    -> round -3%  (secondary)
//     R11 VALU-busy spin             -> round -1%  (clock droop ruled out)
//     R12 atomic-swap store + poll4  -> round +32% (REGRESSION, reverted)
//     R14 no-vmcnt barriers + storer-poll exemption -> +7% (REGRESSION:
//         store acks already off-path; double-poll lengthens detect)
//   => round = agent store->MALL visibility + producer skew + one poll
//      sampling quantum + ~0.5us on-chain compute ~= 2.2us. 4097 sequential
//      handshakes = ~9.0 ms: the latency floor of this protocol. Not a
//      counter-visible roofline (VALUBusy 22%, HBM 1%) - a latency floor.
//   Algorithmic escapes audited: single-CU weight residency (16MB) exceeds
//   VGPR+LDS; weight streaming (64GB) exceeds HBM time budget; nonlinear
//   recurrence forbids scan; merged-layer (R9) and wide-block (R8) variants
//   measured worse.
//   Structure kept: L1 dot split (Wih1 term off-chain, one round stale, in
//   registers), single-tag chain polls, parallel 32-lane gate tails,
//   64B contiguous packet lines (tid<8), stride-64 conflict-free LDS reads,
//   1024 thr/block, 1 block/CU, EWMA pacing, v_fmac spin waits.
// ---------------------------------------------------------------------------

#define T_STEPS 4096
#define HID 1024
#define UPB 8            // hidden units per block
#define NBLK 256         // persistent blocks (128 per layer)

typedef unsigned long long u64;

#define AGENT_LD64(p) __hip_atomic_load((p), __ATOMIC_RELAXED, __HIP_MEMORY_SCOPE_AGENT)
#define AGENT_ST64(p, v) __hip_atomic_store((p), (v), __ATOMIC_RELAXED, __HIP_MEMORY_SCOPE_AGENT)

__device__ __forceinline__ u64 pack_h(float h, int tag) {
  return (u64)__float_as_uint(h) | ((u64)(unsigned)tag << 32);
}
__device__ __forceinline__ float pkt_val(u64 v) { return __uint_as_float((unsigned)v); }
__device__ __forceinline__ int pkt_tag(u64 v) { return (int)(v >> 32); }

__device__ __forceinline__ float fast_sigm(float x) {
  return __builtin_amdgcn_rcpf(1.f + __expf(-x));
}
__device__ __forceinline__ float fast_tanh(float x) {
  return 2.f * __builtin_amdgcn_rcpf(1.f + __expf(-2.f * x)) - 1.f;
}

// Busy-spin unit: 8 dependent v_fmac_f32 (volatile -> always issued).
// Keeps the SIMD issue slots active during waits (clock hold); ~30-50cy
// per call = poll pacing similar to s_sleep(1).
__device__ __forceinline__ void spin_fma(float* j) {
  const float eps = 1.0e-12f;
#pragma unroll
  for (int z = 0; z < 8; z++)
    asm volatile("v_fmac_f32 %0, %1, %1" : "+v"(*j) : "v"(eps));
}

// Pace: spin (no memory traffic, VALU busy) until ~half the expected period
// has elapsed since the previous detect. per==0 disables (warmup rounds).
__device__ __forceinline__ void pace_wait(u64 t_last, u64 per, float* j) {
  if (per) {
    u64 target = t_last + (per >> 1);
    while ((long long)(__builtin_amdgcn_s_memrealtime() - target) < 0)
      spin_fma(j);
  }
}
// EWMA period update (clamped against scheduler hiccups).
__device__ __forceinline__ void pace_update(u64* t_last, u64* per) {
  u64 now = __builtin_amdgcn_s_memrealtime();
  if (*t_last) {
    u64 d = now - *t_last;
    if (d > 1024) d = 1024;                 // ~10 us cap @100 MHz wall clock
    *per = *per ? ((*per * 3 + d) >> 2) : d;
  }
  *t_last = now;
}

__global__ void k_clear(u64* __restrict__ p, long n) {
  long i = (long)blockIdx.x * blockDim.x + threadIdx.x;
  long stride = (long)gridDim.x * blockDim.x;
  for (; i < n; i += stride) p[i] = 0ULL;
}

__global__ void k_prep(const float* __restrict__ inputs,
                       const float* __restrict__ b_ih0, const float* __restrict__ b_hh0,
                       const float* __restrict__ b_ih1, const float* __restrict__ b_hh1,
                       float* __restrict__ xg, float* __restrict__ bsum0,
                       float* __restrict__ b1sum) {
  int i = blockIdx.x * 256 + threadIdx.x;   // grid covers 262144
  if (i < T_STEPS * 64) {
    int t = i >> 6, d = i & 63;
    // x[t] = inputs[sample = t%32, step = t/32, :]
    xg[i] = inputs[(t & 31) * 8192 + (t >> 5) * 64 + d];
  }
  if (i < 4096) {
    bsum0[i] = b_ih0[i] + b_hh0[i];
    b1sum[i] = b_ih1[i] + b_hh1[i];
  }
}

// C = A @ B^T + bias.  A: M x K, B: N x K (both row-major, K contiguous).
// 128x128 tile, BK=8, 256 threads, 8x8 micro-tile per thread.
__global__ __launch_bounds__(256) void gemm_nt(
    const float* __restrict__ A, const float* __restrict__ B,
    const float* __restrict__ bias, float* __restrict__ C,
    int M, int N, int K, int mode) {
  __shared__ float As[8][128];
  __shared__ float Bs[8][128];
  const int tid = threadIdx.x;
  const int bm = blockIdx.x * 128;
  const int bn = blockIdx.y * 128;
  const int tm = tid >> 4;
  const int tn = tid & 15;
  const int lr = tid >> 1;
  const int lk = (tid & 1) * 4;

  float acc[8][8];
#pragma unroll
  for (int i = 0; i < 8; i++)
#pragma unroll
    for (int j = 0; j < 8; j++) acc[i][j] = 0.f;

  const float* Ap = A + (long)(bm + lr) * K + lk;
  const bool bvalid = (bn + lr) < N;
  const float* Bp = B + (long)(bvalid ? (bn + lr) : 0) * K + lk;

  for (int k0 = 0; k0 < K; k0 += 8) {
    float4 av = *(const float4*)(Ap + k0);
    float4 bv = bvalid ? *(const float4*)(Bp + k0) : make_float4(0.f, 0.f, 0.f, 0.f);
    As[lk + 0][lr] = av.x; As[lk + 1][lr] = av.y;
    As[lk + 2][lr] = av.z; As[lk + 3][lr] = av.w;
    Bs[lk + 0][lr] = bv.x; Bs[lk + 1][lr] = bv.y;
    Bs[lk + 2][lr] = bv.z; Bs[lk + 3][lr] = bv.w;
    __syncthreads();
#pragma unroll
    for (int kk = 0; kk < 8; kk++) {
      float a[8], b[8];
      *(float4*)&a[0] = *(const float4*)&As[kk][tm * 8];
      *(float4*)&a[4] = *(const float4*)&As[kk][tm * 8 + 4];
      *(float4*)&b[0] = *(const float4*)&Bs[kk][tn * 8];
      *(float4*)&b[4] = *(const float4*)&Bs[kk][tn * 8 + 4];
#pragma unroll
      for (int i = 0; i < 8; i++)
#pragma unroll
        for (int j = 0; j < 8; j++) acc[i][j] = fmaf(a[i], b[j], acc[i][j]);
    }
    __syncthreads();
  }

  const int n0 = bn + tn * 8;
  if (n0 < N) {
    float bb[8];
#pragma unroll
    for (int j = 0; j < 8; j++) bb[j] = bias[n0 + j];
#pragma unroll
    for (int i = 0; i < 8; i++) {
      int m = bm + tm * 8 + i;
      float4 v0, v1;
      v0.x = acc[i][0] + bb[0]; v0.y = acc[i][1] + bb[1];
      v0.z = acc[i][2] + bb[2]; v0.w = acc[i][3] + bb[3];
      v1.x = acc[i][4] + bb[4]; v1.y = acc[i][5] + bb[5];
      v1.z = acc[i][6] + bb[6]; v1.w = acc[i][7] + bb[7];
      if (mode == 0) {
        long o = (long)m * N + n0;
        *(float4*)&C[o] = v0; *(float4*)&C[o + 4] = v1;
      } else {
        long o = (long)(m & 31) * 8192 + (long)(m >> 5) * 64 + n0;
        *(float4*)&C[o] = v0; *(float4*)&C[o + 4] = v1;
      }
    }
  }
}

// Fused 2-layer recurrence. 256 blocks x 1024 threads (16 waves), 1 block/CU.
// Wave w owns local rows 2w, 2w+1 (row rr: gate rr>>3, unit rr&7);
// lane covers k = lane + 64*m (stride-64 LDS reads: conflict-free).
__global__ __launch_bounds__(1024, 1) void lstm_fused(
    const float* __restrict__ pre0,   // T x 4096 (layer-0 biases included)
    const float* __restrict__ Whh0,   // 4096 x 1024
    const float* __restrict__ Wih1,   // 4096 x 1024
    const float* __restrict__ Whh1,   // 4096 x 1024
    const float* __restrict__ b1sum,  // 4096
    u64* __restrict__ pk0,            // T x 1024 packets {h0, tag=t+1}
    u64* __restrict__ pk1,            // T x 1024 packets {h1, tag=t+1}
    float* __restrict__ h1_hist) {    // T x 1024 plain (for output GEMM)
  __shared__ float ha_lds[HID];       // 4 KB
  __shared__ float hb_lds[HID];       // 4 KB (layer-1 only)
  __shared__ float scr[32];
  const int b = blockIdx.x;
  const int tid = threadIdx.x;
  const int wave = tid >> 6;          // wave w owns local rows 2w, 2w+1
  const int lane = tid & 63;
  float junk = 0.f;                   // spin accumulator (kept live below)

  if (b < 128) {
    // ----------------------------- layer 0 -------------------------------
    const int j0 = b * UPB;
    // weight rows in VGPRs: w0[m] = Whh0[row(2w)][lane+64m], w1 likewise
    float w0[16], w1[16];
    {
      int r0 = 2 * wave, r1 = 2 * wave + 1;
      const float* s0 = Whh0 + (long)((r0 >> 3) * HID + j0 + (r0 & 7)) * HID + lane;
      const float* s1 = Whh0 + (long)((r1 >> 3) * HID + j0 + (r1 & 7)) * HID + lane;
#pragma unroll
      for (int m = 0; m < 16; m++) { w0[m] = s0[m << 6]; w1[m] = s1[m << 6]; }
    }
    float c_state = 0.f;              // valid in tid 0..7
    u64 t_last = 0, per = 0;          // pacing state (100 MHz wall ticks)
    __syncthreads();

    for (int t = 0; t < T_STEPS; t++) {
      float preval = 0.f;             // in-register; load overlaps the poll
      if (tid < 32)
        preval = pre0[(long)t * 4096 + ((tid >> 3) << 10) + j0 + (tid & 7)];

      if (t > 0) {
        const u64* p = pk0 + (long)(t - 1) * HID + tid;
        pace_wait(t_last, per, &junk);
        u64 v;
        for (;;) {
          v = AGENT_LD64(p);
          if (pkt_tag(v) == t) break;
          spin_fma(&junk);            // VALU-busy wait (clock hold)
        }
        pace_update(&t_last, &per);
        ha_lds[tid] = pkt_val(v);
      } else {
        ha_lds[tid] = 0.f;
      }
      __syncthreads();                // B1

      float s0 = 0.f, s1 = 0.f;
#pragma unroll
      for (int m = 0; m < 16; m++) {
        float hv = ha_lds[lane + (m << 6)];
        s0 = fmaf(w0[m], hv, s0);
        s1 = fmaf(w1[m], hv, s1);
      }
#pragma unroll
      for (int off = 32; off >= 1; off >>= 1) {
        s0 += __shfl_xor(s0, off, 64);
        s1 += __shfl_xor(s1, off, 64);
      }
      if (lane == 0) { scr[wave * 2] = s0; scr[wave * 2 + 1] = s1; }
      __syncthreads();                // B2

      // Parallel tail: 32 lanes of wave 0 = one (gate,unit) each.
      if (tid < 32) {
        float sum = scr[tid] + preval;
        float a = ((tid >> 3) == 2) ? fast_tanh(sum) : fast_sigm(sum);
        float af = __shfl(a,  8 + (tid & 7), 64);
        float ag = __shfl(a, 16 + (tid & 7), 64);
        float ao = __shfl(a, 24 + (tid & 7), 64);
        if (tid < 8) {                // a here = sigm(i) of unit tid
          c_state = af * c_state + a * ag;
          float h = ao * fast_tanh(c_state);
          // 8 consecutive u64 = one 64B line: coalesces into one write
          AGENT_ST64(&pk0[(long)t * HID + j0 + tid], pack_h(h, t + 1));
        }
      }
    }
    if (junk == 123456.789f) ha_lds[0] = junk;   // unreachable: keeps junk live
  } else {
    // ----------------------------- layer 1 -------------------------------
    const int j0 = (b - 128) * UPB;
    float wi0[16], wi1[16], wh0[16], wh1[16];
    {
      int r0 = 2 * wave, r1 = 2 * wave + 1;
      long o0 = (long)((r0 >> 3) * HID + j0 + (r0 & 7)) * HID + lane;
      long o1 = (long)((r1 >> 3) * HID + j0 + (r1 & 7)) * HID + lane;
      const float* a0 = Wih1 + o0; const float* a1 = Wih1 + o1;
      const float* c0 = Whh1 + o0; const float* c1 = Whh1 + o1;
#pragma unroll
      for (int m = 0; m < 16; m++) {
        wi0[m] = a0[m << 6]; wi1[m] = a1[m << 6];
        wh0[m] = c0[m << 6]; wh1[m] = c1[m << 6];
      }
    }
    float b1v = 0.f;                  // in-register bias (gate,unit) of tid<32
    if (tid < 32) b1v = b1sum[((tid >> 3) << 10) + j0 + (tid & 7)];
    float c_state = 0.f;              // valid in tid 0..7
    u64 t_last = 0, per = 0;
    __syncthreads();

    // ---- setup: sA = Wih1 @ h0[0] per-lane partials (off-chain) ----------
    float sA0 = 0.f, sA1 = 0.f;
    {
      const u64* p = pk0 + tid;
      u64 v;
      for (;;) {
        v = AGENT_LD64(p);
        if (pkt_tag(v) == 1) break;
        spin_fma(&junk);
      }
      ha_lds[tid] = pkt_val(v);
      __syncthreads();
#pragma unroll
      for (int m = 0; m < 16; m++) {
        float av = ha_lds[lane + (m << 6)];
        sA0 = fmaf(wi0[m], av, sA0);
        sA1 = fmaf(wi1[m], av, sA1);
      }
    }

    for (int r = 1; r <= T_STEPS; r++) {   // computes h1[r-1]
      // ---- chain: detect pk1[r-2] only (single tag) ----------------------
      if (r >= 2) {
        const u64* p = pk1 + (long)(r - 2) * HID + tid;
        pace_wait(t_last, per, &junk);
        u64 v;
        for (;;) {
          v = AGENT_LD64(p);
          if (pkt_tag(v) == r - 1) break;
          spin_fma(&junk);
        }
        pace_update(&t_last, &per);
        hb_lds[tid] = pkt_val(v);
      } else {
        hb_lds[tid] = 0.f;
      }
      __syncthreads();                // B1

      // ---- on-chain dot: Whh1 term only (sA carried in registers) --------
      float s0 = sA0, s1 = sA1;
#pragma unroll
      for (int m = 0; m < 16; m++) {
        float bv = hb_lds[lane + (m << 6)];
        s0 = fmaf(wh0[m], bv, s0);
        s1 = fmaf(wh1[m], bv, s1);
      }
#pragma unroll
      for (int off = 32; off >= 1; off >>= 1) {
        s0 += __shfl_xor(s0, off, 64);
        s1 += __shfl_xor(s1, off, 64);
      }
      if (lane == 0) { scr[wave * 2] = s0; scr[wave * 2 + 1] = s1; }
      __syncthreads();                // B2

      // ---- parallel tail + chain store -----------------------------------
      if (tid < 32) {
        float sum = scr[tid] + b1v;
        float a = ((tid >> 3) == 2) ? fast_tanh(sum) : fast_sigm(sum);
        float af = __shfl(a,  8 + (tid & 7), 64);
        float ag = __shfl(a, 16 + (tid & 7), 64);
        float ao = __shfl(a, 24 + (tid & 7), 64);
        if (tid < 8) {
          c_state = af * c_state + a * ag;
          float h = ao * fast_tanh(c_state);
          AGENT_ST64(&pk1[(long)(r - 1) * HID + j0 + tid], pack_h(h, r));
          h1_hist[(long)(r - 1) * HID + j0 + tid] = h;   // for out GEMM
        }
      }

      // ---- off-chain (store->detect shadow): sA for next round -----------
      if (r < T_STEPS) {
        const u64* p = pk0 + (long)r * HID + tid;   // h0[r], one round stale
        u64 v;
        for (;;) {
          v = AGENT_LD64(p);
          if (pkt_tag(v) == r + 1) break;
          spin_fma(&junk);
        }
        ha_lds[tid] = pkt_val(v);
        __syncthreads();              // B3 (off-chain)
        float n0 = 0.f, n1 = 0.f;
#pragma unroll
        for (int m = 0; m < 16; m++) {
          float av = ha_lds[lane + (m << 6)];
          n0 = fmaf(wi0[m], av, n0);
          n1 = fmaf(wi1[m], av, n1);
        }
        sA0 = n0; sA1 = n1;
      }
    }
    if (junk == 123456.789f) hb_lds[0] = junk;   // unreachable: keeps junk live
  }
}

extern "C" void kernel_launch(void* const* d_in, const int* in_sizes, int n_in,
                              void* d_out, int out_size, void* d_ws, size_t ws_size,
                              hipStream_t stream) {
  const float* inputs = (const float*)d_in[0];
  const float* W_in  = (const float*)d_in[1];
  const float* b_in  = (const float*)d_in[2];
  const float* W_ih0 = (const float*)d_in[3];
  const float* W_hh0 = (const float*)d_in[4];
  const float* b_ih0 = (const float*)d_in[5];
  const float* b_hh0 = (const float*)d_in[6];
  const float* W_ih1 = (const float*)d_in[7];
  const float* W_hh1 = (const float*)d_in[8];
  const float* b_ih1 = (const float*)d_in[9];
  const float* b_hh1 = (const float*)d_in[10];
  const float* W_out = (const float*)d_in[11];
  const float* b_out = (const float*)d_in[12];
  float* out = (float*)d_out;

  char* ws = (char*)d_ws;
  float* pre_big = (float*)(ws);                          // [0,64) MB: pre0
  u64*   pk0     = (u64*)  (ws + ((size_t)64 << 20));     // [64,96) MB
  u64*   pk1     = (u64*)  (ws + ((size_t)96 << 20));     // [96,128) MB
  float* zbuf    = (float*)(ws + ((size_t)128 << 20));    // [128,144) MB: z, then h1
  float* xg      = (float*)(ws + ((size_t)144 << 20));    // 1 MB
  float* bsum0   = (float*)(ws + ((size_t)145 << 20));    // 16 KB
  float* b1sum   = (float*)(ws + ((size_t)145 << 20) + 16384);

  // 0) invalidate packet tags (64 MB zeros) + gather x + combine biases
  k_clear<<<2048, 256, 0, stream>>>(pk0, (long)2 * T_STEPS * HID);
  k_prep<<<1024, 256, 0, stream>>>(inputs, b_ih0, b_hh0, b_ih1, b_hh1,
                                   xg, bsum0, b1sum);
  // 1) z = x @ W_in^T + b_in            (4096 x 1024, K=64)
  gemm_nt<<<dim3(32, 8), 256, 0, stream>>>(xg, W_in, b_in, zbuf,
                                           T_STEPS, HID, 64, 0);
  // 2) pre0 = z @ W_ih0^T + (b_ih0+b_hh0)   (4096 x 4096, K=1024)
  gemm_nt<<<dim3(32, 32), 256, 0, stream>>>(zbuf, W_ih0, bsum0, pre_big,
                                            T_STEPS, 4096, HID, 0);
  // 3) fused pipelined 2-layer recurrence (h1 -> zbuf)
  lstm_fused<<<NBLK, 1024, 0, stream>>>(pre_big, W_hh0, W_ih1, W_hh1, b1sum,
                                        pk0, pk1, zbuf);
  // 4) y = h1 @ W_out^T + b_out, scattered to (samples, steps, out)
  gemm_nt<<<dim3(32, 1), 256, 0, stream>>>(zbuf, W_out, b_out, out,
                                           T_STEPS, 64, HID, 1);
}